// Round 1
// baseline (1443.937 us; speedup 1.0000x reference)
//
#include <hip/hip_runtime.h>
#include <hip/hip_bf16.h>

#define DEV __device__ __forceinline__

typedef __attribute__((ext_vector_type(8))) short bhalf8;
typedef __attribute__((ext_vector_type(4))) float floatx4;

constexpr int NB = 16384;   // batch
constexpr int NV = 4096;    // visible
constexpr int NH = 1024;    // hidden
constexpr float MOM = 0.5f;
constexpr float WD  = 1e-4f;
constexpr float LRB = 1e-3f / 16384.0f;

constexpr int BM = 128, BN = 128, BK = 32;
constexpr int LSTR = BK + 8;        // 40 shorts = 80B row stride: 16B aligned, ~2-way banks

DEV unsigned short f2bf(float f) {
  unsigned u = __builtin_bit_cast(unsigned, f);
  u += 0x7FFFu + ((u >> 16) & 1u);      // RNE
  return (unsigned short)(u >> 16);
}
DEV float sigm(float x) { return 1.0f / (1.0f + __expf(-x)); }

// ---------------- W -> bf16 W and W^T ----------------
__global__ void convw_kernel(const float* __restrict__ W,
                             unsigned short* __restrict__ Wbf,
                             unsigned short* __restrict__ WT) {
  __shared__ unsigned short t[32][33];
  const int h0 = blockIdx.x * 32, v0 = blockIdx.y * 32;
  const int lx = threadIdx.x, ly = threadIdx.y;
#pragma unroll
  for (int s = 0; s < 32; s += 8) {
    float f = W[(size_t)(v0 + ly + s) * NH + h0 + lx];
    unsigned short b = f2bf(f);
    Wbf[(size_t)(v0 + ly + s) * NH + h0 + lx] = b;
    t[ly + s][lx] = b;
  }
  __syncthreads();
#pragma unroll
  for (int s = 0; s < 32; s += 8) {
    WT[(size_t)(h0 + ly + s) * NV + v0 + lx] = t[lx][ly + s];
  }
}

// ---------------- fused GEMM: C = sigmoid(A @ B^T-ish + bias), epilogues ----------------
// A: row-major [M][K] (f32 if MODE==0, bf16 otherwise)
// Bsrc: row-major [N][K] bf16 (so B_lds[n][k] staging is contiguous)
// MODE 0: pos hidden  -> Pout = acts (0/1 bf16), colsum += sum_rows(p), uses rand_h0
// MODE 1: neg visible -> Pout = p bf16, colsum += sum_rows(inputs - p), err += (inputs-p)^2
// MODE 2: neg hidden  -> Pout = p bf16, colsum += sum_rows(p)
template <int MODE>
__global__ __launch_bounds__(256, 2)
void gemm_fused(const void* __restrict__ Av,
                const unsigned short* __restrict__ Bsrc,
                int M, int N, int K,
                const float* __restrict__ bias,
                const float* __restrict__ rand_h0,
                unsigned short* __restrict__ Pout,
                float* __restrict__ colsum,
                const float* __restrict__ inpf,
                float* __restrict__ err_accum) {
  __shared__ __align__(16) unsigned short As[2][BM * LSTR];
  __shared__ __align__(16) unsigned short Bs[2][BN * LSTR];
  __shared__ float ered[4];

  const int tid = threadIdx.x;
  const int wid = tid >> 6, lane = tid & 63;
  const int wm = wid >> 1, wn = wid & 1;
  const int lr = lane & 15, kg = lane >> 4;
  const int m0 = blockIdx.y * BM, n0 = blockIdx.x * BN;

  const int s_row = tid >> 2;        // 0..63 (+64 for chunk 1)
  const int s_kc  = (tid & 3) * 8;   // k offset within BK

  const float* Af = (const float*)Av;
  const unsigned short* Ab = (const unsigned short*)Av;

  floatx4 acc[4][4] = {};
  bhalf8 ra[2], rb[2];

  auto load_tile = [&](int kt) {
    const int kb = kt * BK + s_kc;
#pragma unroll
    for (int c = 0; c < 2; ++c) {
      const int row = s_row + c * 64;
      if (MODE == 0) {
        const float* p = Af + (size_t)(m0 + row) * K + kb;
        floatx4 lo = *(const floatx4*)p;
        floatx4 hi = *(const floatx4*)(p + 4);
        bhalf8 r;
        r[0] = (short)f2bf(lo[0]); r[1] = (short)f2bf(lo[1]);
        r[2] = (short)f2bf(lo[2]); r[3] = (short)f2bf(lo[3]);
        r[4] = (short)f2bf(hi[0]); r[5] = (short)f2bf(hi[1]);
        r[6] = (short)f2bf(hi[2]); r[7] = (short)f2bf(hi[3]);
        ra[c] = r;
      } else {
        ra[c] = *(const bhalf8*)(Ab + (size_t)(m0 + row) * K + kb);
      }
      rb[c] = *(const bhalf8*)(Bsrc + (size_t)(n0 + row) * K + kb);
    }
  };
  auto store_tile = [&](int buf) {
#pragma unroll
    for (int c = 0; c < 2; ++c) {
      const int row = s_row + c * 64;
      *(bhalf8*)&As[buf][row * LSTR + s_kc] = ra[c];
      *(bhalf8*)&Bs[buf][row * LSTR + s_kc] = rb[c];
    }
  };
  auto compute = [&](int buf) {
    bhalf8 fa[4], fb[4];
    const unsigned short* pa = &As[buf][(wm * 64 + lr) * LSTR + kg * 8];
    const unsigned short* pb = &Bs[buf][(wn * 64 + lr) * LSTR + kg * 8];
#pragma unroll
    for (int i = 0; i < 4; ++i) fa[i] = *(const bhalf8*)(pa + i * 16 * LSTR);
#pragma unroll
    for (int i = 0; i < 4; ++i) fb[i] = *(const bhalf8*)(pb + i * 16 * LSTR);
#pragma unroll
    for (int mi = 0; mi < 4; ++mi)
#pragma unroll
      for (int ni = 0; ni < 4; ++ni)
        acc[mi][ni] = __builtin_amdgcn_mfma_f32_16x16x32_bf16(fa[mi], fb[ni], acc[mi][ni], 0, 0, 0);
  };

  const int nk = K / BK;
  load_tile(0);
  store_tile(0);
  __syncthreads();
  int cur = 0;
  for (int kt = 0; kt < nk; ++kt) {
    const bool more = (kt + 1 < nk);
    if (more) load_tile(kt + 1);
    compute(cur);
    __syncthreads();
    if (more) store_tile(cur ^ 1);
    __syncthreads();
    cur ^= 1;
  }

  // -------- epilogue --------
  if (MODE == 0 || MODE == 2) {
#pragma unroll
    for (int ni = 0; ni < 4; ++ni) {
      const int col = n0 + wn * 64 + ni * 16 + lr;
      const float b = bias[col];
      const float r0 = (MODE == 0) ? rand_h0[col] : 0.0f;
      float cs = 0.0f;
#pragma unroll
      for (int mi = 0; mi < 4; ++mi) {
        const int rowb = m0 + wm * 64 + mi * 16 + kg * 4;
#pragma unroll
        for (int r = 0; r < 4; ++r) {
          const float p = sigm(acc[mi][ni][r] + b);
          cs += p;
          unsigned short ov;
          if (MODE == 0) ov = (p >= r0) ? (unsigned short)0x3F80u : (unsigned short)0u;
          else           ov = f2bf(p);
          Pout[(size_t)(rowb + r) * N + col] = ov;
        }
      }
      cs += __shfl_xor(cs, 16);
      cs += __shfl_xor(cs, 32);
      if (kg == 0) atomicAdd(&colsum[col], cs);
    }
  } else {  // MODE 1: neg visible
    float esum = 0.0f;
#pragma unroll
    for (int ni = 0; ni < 4; ++ni) {
      const int col = n0 + wn * 64 + ni * 16 + lr;
      const float b = bias[col];
      float cs = 0.0f;
#pragma unroll
      for (int mi = 0; mi < 4; ++mi) {
        const int rowb = m0 + wm * 64 + mi * 16 + kg * 4;
#pragma unroll
        for (int r = 0; r < 4; ++r) {
          const size_t idx = (size_t)(rowb + r) * N + col;
          const float p = sigm(acc[mi][ni][r] + b);
          Pout[idx] = f2bf(p);
          const float d = inpf[idx] - p;
          cs += d;
          esum += d * d;
        }
      }
      cs += __shfl_xor(cs, 16);
      cs += __shfl_xor(cs, 32);
      if (kg == 0) atomicAdd(&colsum[col], cs);
    }
    esum += __shfl_xor(esum, 1);
    esum += __shfl_xor(esum, 2);
    esum += __shfl_xor(esum, 4);
    esum += __shfl_xor(esum, 8);
    esum += __shfl_xor(esum, 16);
    esum += __shfl_xor(esum, 32);
    if (lane == 0) ered[wid] = esum;
    __syncthreads();
    if (tid == 0) atomicAdd(err_accum, ered[0] + ered[1] + ered[2] + ered[3]);
  }
}

// ---------------- TN GEMM: diff[v][h] += sgn * sum_k A[k][v] * B[k][h] ----------------
// A: [Ktot][Mg] (f32 if AF32 else bf16), B: [Ktot][Ng] bf16. Split-K via blockIdx.z.
template <bool AF32>
__global__ __launch_bounds__(256, 2)
void gemm_tn(const void* __restrict__ Av, const unsigned short* __restrict__ Bsrc,
             int Mg, int Ng, int ksplit, float sgn, float* __restrict__ outd) {
  __shared__ __align__(16) unsigned short As[2][BM * LSTR];
  __shared__ __align__(16) unsigned short Bs[2][BN * LSTR];

  const int tid = threadIdx.x;
  const int wid = tid >> 6, lane = tid & 63;
  const int wm = wid >> 1, wn = wid & 1;
  const int lr = lane & 15, kg = lane >> 4;
  const int m0 = blockIdx.y * BM, n0 = blockIdx.x * BN;
  const int kb0 = blockIdx.z * ksplit;

  const int s_m  = tid & 127;          // m (and n) index within tile
  const int s_kh = (tid >> 7) * 8;     // 0 or 8; +16 for chunk 1

  const float* Af = (const float*)Av;
  const unsigned short* Ab = (const unsigned short*)Av;

  floatx4 acc[4][4] = {};
  bhalf8 ra[2], rb[2];

  auto load_tile = [&](int kt) {
    const int kb = kb0 + kt * BK;
#pragma unroll
    for (int c = 0; c < 2; ++c) {
      const int k0 = kb + s_kh + c * 16;
      bhalf8 r, rr;
      if (AF32) {
#pragma unroll
        for (int j = 0; j < 8; ++j) r[j] = (short)f2bf(Af[(size_t)(k0 + j) * Mg + m0 + s_m]);
      } else {
#pragma unroll
        for (int j = 0; j < 8; ++j) r[j] = (short)Ab[(size_t)(k0 + j) * Mg + m0 + s_m];
      }
#pragma unroll
      for (int j = 0; j < 8; ++j) rr[j] = (short)Bsrc[(size_t)(k0 + j) * Ng + n0 + s_m];
      ra[c] = r;
      rb[c] = rr;
    }
  };
  auto store_tile = [&](int buf) {
#pragma unroll
    for (int c = 0; c < 2; ++c) {
      const int k0 = s_kh + c * 16;
      *(bhalf8*)&As[buf][s_m * LSTR + k0] = ra[c];
      *(bhalf8*)&Bs[buf][s_m * LSTR + k0] = rb[c];
    }
  };
  auto compute = [&](int buf) {
    bhalf8 fa[4], fb[4];
    const unsigned short* pa = &As[buf][(wm * 64 + lr) * LSTR + kg * 8];
    const unsigned short* pb = &Bs[buf][(wn * 64 + lr) * LSTR + kg * 8];
#pragma unroll
    for (int i = 0; i < 4; ++i) fa[i] = *(const bhalf8*)(pa + i * 16 * LSTR);
#pragma unroll
    for (int i = 0; i < 4; ++i) fb[i] = *(const bhalf8*)(pb + i * 16 * LSTR);
#pragma unroll
    for (int mi = 0; mi < 4; ++mi)
#pragma unroll
      for (int ni = 0; ni < 4; ++ni)
        acc[mi][ni] = __builtin_amdgcn_mfma_f32_16x16x32_bf16(fa[mi], fb[ni], acc[mi][ni], 0, 0, 0);
  };

  const int nk = ksplit / BK;
  load_tile(0);
  store_tile(0);
  __syncthreads();
  int cur = 0;
  for (int kt = 0; kt < nk; ++kt) {
    const bool more = (kt + 1 < nk);
    if (more) load_tile(kt + 1);
    compute(cur);
    __syncthreads();
    if (more) store_tile(cur ^ 1);
    __syncthreads();
    cur ^= 1;
  }

#pragma unroll
  for (int mi = 0; mi < 4; ++mi) {
    const int rowb = m0 + wm * 64 + mi * 16 + kg * 4;
#pragma unroll
    for (int ni = 0; ni < 4; ++ni) {
      const int col = n0 + wn * 64 + ni * 16 + lr;
#pragma unroll
      for (int r = 0; r < 4; ++r)
        atomicAdd(&outd[(size_t)(rowb + r) * Ng + col], sgn * acc[mi][ni][r]);
    }
  }
}

// ---------------- weight update ----------------
__global__ void wupdate_kernel(const float* __restrict__ W, const float* __restrict__ wm,
                               const float* __restrict__ diff, float* __restrict__ outW) {
  const int i = blockIdx.x * blockDim.x + threadIdx.x;   // over NV*NH/4
  const floatx4 w = ((const floatx4*)W)[i];
  const floatx4 m = ((const floatx4*)wm)[i];
  const floatx4 d = ((const floatx4*)diff)[i];
  floatx4 o;
#pragma unroll
  for (int j = 0; j < 4; ++j) o[j] = (w[j] + (m[j] * MOM + d[j]) * LRB) * (1.0f - WD);
  ((floatx4*)outW)[i] = o;
}

// ---------------- bias updates + error ----------------
__global__ void biaserr_kernel(const float* __restrict__ vb, const float* __restrict__ vbm,
                               const float* __restrict__ vbcs,
                               const float* __restrict__ hb, const float* __restrict__ hbm,
                               const float* __restrict__ phpcs, const float* __restrict__ nhpcs,
                               const float* __restrict__ err, float* __restrict__ out) {
  const int i = blockIdx.x * blockDim.x + threadIdx.x;
  if (i < NV) out[1 + (size_t)NV * NH + i] = vb[i] + (vbm[i] * MOM + vbcs[i]) * LRB;
  if (i < NH) out[1 + (size_t)NV * NH + NV + i] = hb[i] + (hbm[i] * MOM + (phpcs[i] - nhpcs[i])) * LRB;
  if (i == 0) out[0] = err[0];
}

extern "C" void kernel_launch(void* const* d_in, const int* in_sizes, int n_in,
                              void* d_out, int out_size, void* d_ws, size_t ws_size,
                              hipStream_t stream) {
  const float* inputs  = (const float*)d_in[0];
  const float* W       = (const float*)d_in[1];
  const float* vb      = (const float*)d_in[2];
  const float* hb      = (const float*)d_in[3];
  const float* wmom    = (const float*)d_in[4];
  const float* vbmom   = (const float*)d_in[5];
  const float* hbmom   = (const float*)d_in[6];
  const float* rand_h0 = (const float*)d_in[7];
  // d_in[8] = rand_hk: unused by the reference semantics

  char* ws = (char*)d_ws;
  size_t off = 0;
  auto take = [&](size_t b) { size_t r = off; off = (off + b + 255) & ~(size_t)255; return r; };
  unsigned short* Wbf  = (unsigned short*)(ws + take((size_t)NV * NH * 2));
  unsigned short* WT   = (unsigned short*)(ws + take((size_t)NV * NH * 2));
  unsigned short* acts = (unsigned short*)(ws + take((size_t)NB * NH * 2));
  unsigned short* nhp  = (unsigned short*)(ws + take((size_t)NB * NH * 2));
  unsigned short* nvp  = (unsigned short*)(ws + take((size_t)NB * NV * 2));
  const size_t diff_off = take((size_t)NV * NH * 4);
  float* diff = (float*)(ws + diff_off);
  const size_t red_bytes = (size_t)(NH + NH + NV + 64) * 4;
  const size_t red_off = take(red_bytes);
  float* phpcs = (float*)(ws + red_off);
  float* nhpcs = phpcs + NH;
  float* vbcs  = nhpcs + NH;
  float* errp  = vbcs + NV;

  // zero accumulators (diff + reduction region are contiguous)
  hipMemsetAsync(ws + diff_off, 0, (red_off - diff_off) + red_bytes, stream);

  convw_kernel<<<dim3(NH / 32, NV / 32), dim3(32, 8), 0, stream>>>(W, Wbf, WT);

  // 1) pos hidden: php/acts = f(inputs @ W + hb)
  gemm_fused<0><<<dim3(NH / BN, NB / BM), 256, 0, stream>>>(
      inputs, WT, NB, NH, NV, hb, rand_h0, acts, phpcs, nullptr, nullptr);
  // 2) neg visible: nvp = f(acts @ W^T + vb); fused error + vb colsum
  gemm_fused<1><<<dim3(NV / BN, NB / BM), 256, 0, stream>>>(
      acts, Wbf, NB, NV, NH, vb, nullptr, nvp, vbcs, inputs, errp);
  // 3) neg hidden: nhp = f(nvp @ W + hb)
  gemm_fused<2><<<dim3(NH / BN, NB / BM), 256, 0, stream>>>(
      nvp, WT, NB, NH, NV, hb, nullptr, nhp, nhpcs, nullptr, nullptr);

  // 4) diff = inputs^T @ acts - nvp^T @ nhp   (split-K=4, atomic accumulate)
  constexpr int NSPLIT = 4;
  gemm_tn<true><<<dim3(NH / BN, NV / BM, NSPLIT), 256, 0, stream>>>(
      inputs, acts, NV, NH, NB / NSPLIT, 1.0f, diff);
  gemm_tn<false><<<dim3(NH / BN, NV / BM, NSPLIT), 256, 0, stream>>>(
      nvp, nhp, NV, NH, NB / NSPLIT, -1.0f, diff);

  // 5) parameter updates + error
  wupdate_kernel<<<dim3((NV * NH / 4) / 256), 256, 0, stream>>>(W, wmom, diff, (float*)d_out + 1);
  biaserr_kernel<<<dim3(16), 256, 0, stream>>>(vb, vbmom, vbcs, hb, hbmom, phpcs, nhpcs, errp,
                                               (float*)d_out);
}

// Round 2
// 1238.250 us; speedup vs baseline: 1.1661x; 1.1661x over previous
//
#include <hip/hip_runtime.h>
#include <hip/hip_bf16.h>

#define DEV __device__ __forceinline__

typedef __attribute__((ext_vector_type(8))) short bhalf8;
typedef __attribute__((ext_vector_type(4))) float floatx4;

constexpr int NB = 16384;   // batch
constexpr int NV = 4096;    // visible
constexpr int NH = 1024;    // hidden
constexpr float MOM = 0.5f;
constexpr float WD  = 1e-4f;
constexpr float LRB = 1e-3f / 16384.0f;

constexpr int BM = 128, BN = 128, BK = 32;   // linear LDS rows of 32 shorts = 64B

DEV unsigned short f2bf(float f) {
  unsigned u = __builtin_bit_cast(unsigned, f);
  u += 0x7FFFu + ((u >> 16) & 1u);      // RNE
  return (unsigned short)(u >> 16);
}
DEV float bf2f(unsigned short u) {
  unsigned x = ((unsigned)u) << 16;
  return __builtin_bit_cast(float, x);
}
DEV float sigm(float x) { return 1.0f / (1.0f + __expf(-x)); }

// async global(per-lane addr) -> LDS(wave-uniform base + lane*16B)
DEV void gl16(const unsigned short* g, unsigned short* l) {
  __builtin_amdgcn_global_load_lds(
      (const __attribute__((address_space(1))) void*)g,
      (__attribute__((address_space(3))) void*)l,
      16, 0, 0);
}

// ---------- f32 [R][C] -> bf16 [R][C] and bf16 [C][R] ----------
__global__ void prep_cvt_t(const float* __restrict__ in,
                           unsigned short* __restrict__ obf,
                           unsigned short* __restrict__ oT, int R, int C) {
  __shared__ unsigned short t[64][72];
  const int c0 = blockIdx.x * 64, r0 = blockIdx.y * 64;
  const int tr = threadIdx.x >> 3, tc = (threadIdx.x & 7) * 8;
#pragma unroll
  for (int s = 0; s < 64; s += 32) {
    const float* p = in + (size_t)(r0 + tr + s) * C + c0 + tc;
    floatx4 lo = *(const floatx4*)p, hi = *(const floatx4*)(p + 4);
    bhalf8 r;
    r[0] = (short)f2bf(lo[0]); r[1] = (short)f2bf(lo[1]);
    r[2] = (short)f2bf(lo[2]); r[3] = (short)f2bf(lo[3]);
    r[4] = (short)f2bf(hi[0]); r[5] = (short)f2bf(hi[1]);
    r[6] = (short)f2bf(hi[2]); r[7] = (short)f2bf(hi[3]);
    *(bhalf8*)(obf + (size_t)(r0 + tr + s) * C + c0 + tc) = r;
    *(bhalf8*)&t[tr + s][tc] = r;
  }
  __syncthreads();
#pragma unroll
  for (int s = 0; s < 64; s += 32) {
    bhalf8 v;
#pragma unroll
    for (int j = 0; j < 8; ++j) v[j] = (short)t[tc + j][tr + s];
    *(bhalf8*)(oT + (size_t)(c0 + tr + s) * R + r0 + tc) = v;
  }
}

// ---------- bf16 [R][C] -> bf16 [C][R] ----------
__global__ void transb(const unsigned short* __restrict__ in,
                       unsigned short* __restrict__ out, int R, int C) {
  __shared__ unsigned short t[64][72];
  const int c0 = blockIdx.x * 64, r0 = blockIdx.y * 64;
  const int tr = threadIdx.x >> 3, tc = (threadIdx.x & 7) * 8;
#pragma unroll
  for (int s = 0; s < 64; s += 32) {
    bhalf8 v = *(const bhalf8*)(in + (size_t)(r0 + tr + s) * C + c0 + tc);
    *(bhalf8*)&t[tr + s][tc] = v;
  }
  __syncthreads();
#pragma unroll
  for (int s = 0; s < 64; s += 32) {
    bhalf8 v;
#pragma unroll
    for (int j = 0; j < 8; ++j) v[j] = (short)t[tc + j][tr + s];
    *(bhalf8*)(out + (size_t)(c0 + tr + s) * R + r0 + tc) = v;
  }
}

// ---------------- fused NT GEMM: C = sigmoid(A @ B^T + bias), epilogues ----------------
// A: [M][K] bf16 row-major, B: [N][K] bf16 row-major.
// MODE 0: acts = (p >= rand_h0), colsum += sum_rows(p)
// MODE 1: Pout = p, colsum += sum_rows(in - p), err += (in-p)^2
// MODE 2: Pout = p, colsum += sum_rows(p)
template <int MODE>
__global__ __launch_bounds__(256, 2)
void gemm_fused(const unsigned short* __restrict__ Ab,
                const unsigned short* __restrict__ Bb,
                int N, int K,
                const float* __restrict__ bias,
                const float* __restrict__ rand_h0,
                unsigned short* __restrict__ Pout,
                float* __restrict__ colsum,
                const unsigned short* __restrict__ inbf,
                float* __restrict__ err_accum) {
  __shared__ __align__(1024) unsigned short As[2][BM * BK];
  __shared__ __align__(1024) unsigned short Bs[2][BN * BK];
  __shared__ float ered[4];

  const int tid = threadIdx.x;
  const int wid = tid >> 6, lane = tid & 63;
  const int wm = wid >> 1, wn = wid & 1;
  const int lr = lane & 15, kg = lane >> 4;

  // bijective XCD swizzle (nwg % 8 == 0 for all our grids)
  const int nwg = gridDim.x * gridDim.y;
  const int id = blockIdx.y * gridDim.x + blockIdx.x;
  const int sid = (id & 7) * (nwg >> 3) + (id >> 3);
  const int n0 = (sid % gridDim.x) * BN;
  const int m0 = (sid / gridDim.x) * BM;

  const int srow = wid * 32 + (lane >> 2);     // staged row (issue 0; +16 for issue 1)
  const int scol = (lane & 3) * 8;             // short offset within 32-short row
  const unsigned short* gA = Ab + (size_t)(m0 + srow) * K + scol;
  const unsigned short* gB = Bb + (size_t)(n0 + srow) * K + scol;

  floatx4 acc[4][4] = {};

  auto stage = [&](int buf, int kt) {
    const size_t ko = (size_t)kt * BK;
    gl16(gA + ko,                 &As[buf][(wid * 32) * BK]);
    gl16(gA + ko + (size_t)16 * K, &As[buf][(wid * 32 + 16) * BK]);
    gl16(gB + ko,                 &Bs[buf][(wid * 32) * BK]);
    gl16(gB + ko + (size_t)16 * K, &Bs[buf][(wid * 32 + 16) * BK]);
  };
  auto compute = [&](int buf) {
    bhalf8 fa[4], fb[4];
    const unsigned short* pa = &As[buf][(wm * 64 + lr) * BK + kg * 8];
    const unsigned short* pb = &Bs[buf][(wn * 64 + lr) * BK + kg * 8];
#pragma unroll
    for (int i = 0; i < 4; ++i) fa[i] = *(const bhalf8*)(pa + i * 16 * BK);
#pragma unroll
    for (int i = 0; i < 4; ++i) fb[i] = *(const bhalf8*)(pb + i * 16 * BK);
#pragma unroll
    for (int mi = 0; mi < 4; ++mi)
#pragma unroll
      for (int ni = 0; ni < 4; ++ni)
        acc[mi][ni] = __builtin_amdgcn_mfma_f32_16x16x32_bf16(fa[mi], fb[ni], acc[mi][ni], 0, 0, 0);
  };

  const int nk = K / BK;
  stage(0, 0);
  __syncthreads();
  int cur = 0;
  for (int kt = 0; kt < nk; ++kt) {
    if (kt + 1 < nk) stage(cur ^ 1, kt + 1);
    compute(cur);
    __syncthreads();
    cur ^= 1;
  }

  // -------- epilogue --------
  if (MODE == 0 || MODE == 2) {
#pragma unroll
    for (int ni = 0; ni < 4; ++ni) {
      const int col = n0 + wn * 64 + ni * 16 + lr;
      const float b = bias[col];
      const float r0 = (MODE == 0) ? rand_h0[col] : 0.0f;
      float cs = 0.0f;
#pragma unroll
      for (int mi = 0; mi < 4; ++mi) {
        const int rowb = m0 + wm * 64 + mi * 16 + kg * 4;
#pragma unroll
        for (int r = 0; r < 4; ++r) {
          const float p = sigm(acc[mi][ni][r] + b);
          cs += p;
          unsigned short ov;
          if (MODE == 0) ov = (p >= r0) ? (unsigned short)0x3F80u : (unsigned short)0u;
          else           ov = f2bf(p);
          Pout[(size_t)(rowb + r) * N + col] = ov;
        }
      }
      cs += __shfl_xor(cs, 16);
      cs += __shfl_xor(cs, 32);
      if (kg == 0) atomicAdd(&colsum[col], cs);
    }
  } else {  // MODE 1
    float esum = 0.0f;
#pragma unroll
    for (int ni = 0; ni < 4; ++ni) {
      const int col = n0 + wn * 64 + ni * 16 + lr;
      const float b = bias[col];
      float cs = 0.0f;
#pragma unroll
      for (int mi = 0; mi < 4; ++mi) {
        const int rowb = m0 + wm * 64 + mi * 16 + kg * 4;
#pragma unroll
        for (int r = 0; r < 4; ++r) {
          const size_t idx = (size_t)(rowb + r) * N + col;
          const float p = sigm(acc[mi][ni][r] + b);
          Pout[idx] = f2bf(p);
          const float d = bf2f(inbf[idx]) - p;
          cs += d;
          esum += d * d;
        }
      }
      cs += __shfl_xor(cs, 16);
      cs += __shfl_xor(cs, 32);
      if (kg == 0) atomicAdd(&colsum[col], cs);
    }
    esum += __shfl_xor(esum, 1);
    esum += __shfl_xor(esum, 2);
    esum += __shfl_xor(esum, 4);
    esum += __shfl_xor(esum, 8);
    esum += __shfl_xor(esum, 16);
    esum += __shfl_xor(esum, 32);
    if (lane == 0) ered[wid] = esum;
    __syncthreads();
    if (tid == 0) atomicAdd(err_accum, ered[0] + ered[1] + ered[2] + ered[3]);
  }
}

// ---------------- NT GEMM for associations ----------------
// A: [Mg][ld] bf16, B: [Ng][ld] bf16, split-K over blockIdx.z (separate out buffers).
// EOP 0: out = acc;  EOP 1: out -= acc.
template <int EOP>
__global__ __launch_bounds__(256, 2)
void gemm_nt(const unsigned short* __restrict__ Ab,
             const unsigned short* __restrict__ Bb,
             int Ng, int ld, int ksp, float* __restrict__ outd) {
  __shared__ __align__(1024) unsigned short As[2][BM * BK];
  __shared__ __align__(1024) unsigned short Bs[2][BN * BK];

  const int tid = threadIdx.x;
  const int wid = tid >> 6, lane = tid & 63;
  const int wm = wid >> 1, wn = wid & 1;
  const int lr = lane & 15, kg = lane >> 4;

  const int nwg = gridDim.x * gridDim.y;
  const int id = blockIdx.y * gridDim.x + blockIdx.x;
  const int sid = (id & 7) * (nwg >> 3) + (id >> 3);
  const int n0 = (sid % gridDim.x) * BN;
  const int m0 = (sid / gridDim.x) * BM;
  const size_t kb0 = (size_t)blockIdx.z * ksp;

  const int srow = wid * 32 + (lane >> 2);
  const int scol = (lane & 3) * 8;
  const unsigned short* gA = Ab + (size_t)(m0 + srow) * ld + kb0 + scol;
  const unsigned short* gB = Bb + (size_t)(n0 + srow) * ld + kb0 + scol;

  floatx4 acc[4][4] = {};

  auto stage = [&](int buf, int kt) {
    const size_t ko = (size_t)kt * BK;
    gl16(gA + ko,                  &As[buf][(wid * 32) * BK]);
    gl16(gA + ko + (size_t)16 * ld, &As[buf][(wid * 32 + 16) * BK]);
    gl16(gB + ko,                  &Bs[buf][(wid * 32) * BK]);
    gl16(gB + ko + (size_t)16 * ld, &Bs[buf][(wid * 32 + 16) * BK]);
  };
  auto compute = [&](int buf) {
    bhalf8 fa[4], fb[4];
    const unsigned short* pa = &As[buf][(wm * 64 + lr) * BK + kg * 8];
    const unsigned short* pb = &Bs[buf][(wn * 64 + lr) * BK + kg * 8];
#pragma unroll
    for (int i = 0; i < 4; ++i) fa[i] = *(const bhalf8*)(pa + i * 16 * BK);
#pragma unroll
    for (int i = 0; i < 4; ++i) fb[i] = *(const bhalf8*)(pb + i * 16 * BK);
#pragma unroll
    for (int mi = 0; mi < 4; ++mi)
#pragma unroll
      for (int ni = 0; ni < 4; ++ni)
        acc[mi][ni] = __builtin_amdgcn_mfma_f32_16x16x32_bf16(fa[mi], fb[ni], acc[mi][ni], 0, 0, 0);
  };

  const int nk = ksp / BK;
  stage(0, 0);
  __syncthreads();
  int cur = 0;
  for (int kt = 0; kt < nk; ++kt) {
    if (kt + 1 < nk) stage(cur ^ 1, kt + 1);
    compute(cur);
    __syncthreads();
    cur ^= 1;
  }

  float* od = outd + (size_t)blockIdx.z * (size_t)gridDim.y * BM * Ng;
#pragma unroll
  for (int mi = 0; mi < 4; ++mi) {
    const int rowb = m0 + wm * 64 + mi * 16 + kg * 4;
#pragma unroll
    for (int ni = 0; ni < 4; ++ni) {
      const int col = n0 + wn * 64 + ni * 16 + lr;
#pragma unroll
      for (int r = 0; r < 4; ++r) {
        float* p = &od[(size_t)(rowb + r) * Ng + col];
        if (EOP == 0) *p = acc[mi][ni][r];
        else          *p -= acc[mi][ni][r];
      }
    }
  }
}

// ---------------- weight update ----------------
__global__ void wupdate_kernel(const float* __restrict__ W, const float* __restrict__ wm,
                               const float* __restrict__ d0, const float* __restrict__ d1,
                               float* __restrict__ outW) {
  const int i = blockIdx.x * blockDim.x + threadIdx.x;
  const floatx4 w = ((const floatx4*)W)[i];
  const floatx4 m = ((const floatx4*)wm)[i];
  const floatx4 a = ((const floatx4*)d0)[i];
  const floatx4 b = ((const floatx4*)d1)[i];
  floatx4 o;
#pragma unroll
  for (int j = 0; j < 4; ++j) o[j] = (w[j] + (m[j] * MOM + a[j] + b[j]) * LRB) * (1.0f - WD);
  ((floatx4*)outW)[i] = o;
}

// ---------------- bias updates + error ----------------
__global__ void biaserr_kernel(const float* __restrict__ vb, const float* __restrict__ vbm,
                               const float* __restrict__ vbcs,
                               const float* __restrict__ hb, const float* __restrict__ hbm,
                               const float* __restrict__ phpcs, const float* __restrict__ nhpcs,
                               const float* __restrict__ err, float* __restrict__ out) {
  const int i = blockIdx.x * blockDim.x + threadIdx.x;
  if (i < NV) out[1 + (size_t)NV * NH + i] = vb[i] + (vbm[i] * MOM + vbcs[i]) * LRB;
  if (i < NH) out[1 + (size_t)NV * NH + NV + i] = hb[i] + (hbm[i] * MOM + (phpcs[i] - nhpcs[i])) * LRB;
  if (i == 0) out[0] = err[0];
}

extern "C" void kernel_launch(void* const* d_in, const int* in_sizes, int n_in,
                              void* d_out, int out_size, void* d_ws, size_t ws_size,
                              hipStream_t stream) {
  const float* inputs  = (const float*)d_in[0];
  const float* W       = (const float*)d_in[1];
  const float* vb      = (const float*)d_in[2];
  const float* hb      = (const float*)d_in[3];
  const float* wmom    = (const float*)d_in[4];
  const float* vbmom   = (const float*)d_in[5];
  const float* hbmom   = (const float*)d_in[6];
  const float* rand_h0 = (const float*)d_in[7];

  char* ws = (char*)d_ws;
  size_t off = 0;
  auto take = [&](size_t b) { size_t r = off; off = (off + b + 1023) & ~(size_t)1023; return r; };
  unsigned short* Wbf   = (unsigned short*)(ws + take((size_t)NV * NH * 2));
  unsigned short* WT    = (unsigned short*)(ws + take((size_t)NV * NH * 2));
  unsigned short* inbf  = (unsigned short*)(ws + take((size_t)NB * NV * 2));  // later reused as nvpT
  unsigned short* inT   = (unsigned short*)(ws + take((size_t)NB * NV * 2));
  unsigned short* nvp   = (unsigned short*)(ws + take((size_t)NB * NV * 2));
  unsigned short* acts  = (unsigned short*)(ws + take((size_t)NB * NH * 2));  // later reused as nhp
  unsigned short* actsT = (unsigned short*)(ws + take((size_t)NB * NH * 2));
  unsigned short* nhpT  = (unsigned short*)(ws + take((size_t)NB * NH * 2));
  float* diff0 = (float*)(ws + take((size_t)NV * NH * 4));
  float* diff1 = (float*)(ws + take((size_t)NV * NH * 4));
  const size_t red_bytes = (size_t)(NH + NH + NV + 64) * 4;
  float* phpcs = (float*)(ws + take(red_bytes));
  float* nhpcs = phpcs + NH;
  float* vbcs  = nhpcs + NH;
  float* errp  = vbcs + NV;

  unsigned short* nvpT = inbf;   // overlay: inbf dead after gemm_fused<1>
  unsigned short* nhp  = acts;   // overlay: acts dead after gemm_fused<1>

  hipMemsetAsync(phpcs, 0, red_bytes, stream);

  // prep: bf16 conversions + transposes of inputs and W
  prep_cvt_t<<<dim3(NV / 64, NB / 64), 256, 0, stream>>>(inputs, inbf, inT, NB, NV);
  prep_cvt_t<<<dim3(NH / 64, NV / 64), 256, 0, stream>>>(W, Wbf, WT, NV, NH);

  // 1) pos hidden: acts = (sigm(inbf @ WT^T + hb) >= rand_h0)
  gemm_fused<0><<<dim3(NH / BN, NB / BM), 256, 0, stream>>>(
      inbf, WT, NH, NV, hb, rand_h0, acts, phpcs, nullptr, nullptr);
  transb<<<dim3(NH / 64, NB / 64), 256, 0, stream>>>(acts, actsT, NB, NH);

  // 2) neg visible: nvp = sigm(acts @ Wbf^T + vb); fused err + vb colsum
  gemm_fused<1><<<dim3(NV / BN, NB / BM), 256, 0, stream>>>(
      acts, Wbf, NV, NH, vb, nullptr, nvp, vbcs, inbf, errp);
  transb<<<dim3(NV / 64, NB / 64), 256, 0, stream>>>(nvp, nvpT, NB, NV);

  // 3) neg hidden: nhp = sigm(nvp @ WT^T + hb)
  gemm_fused<2><<<dim3(NH / BN, NB / BM), 256, 0, stream>>>(
      nvp, WT, NH, NV, hb, nullptr, nhp, nhpcs, nullptr, nullptr);
  transb<<<dim3(NH / 64, NB / 64), 256, 0, stream>>>(nhp, nhpT, NB, NH);

  // 4) diff = inputs^T @ acts - nvp^T @ nhp  (split-K=2 into diff0/diff1, no atomics)
  gemm_nt<0><<<dim3(NH / BN, NV / BM, 2), 256, 0, stream>>>(inT, actsT, NH, NB, NB / 2, diff0);
  gemm_nt<1><<<dim3(NH / BN, NV / BM, 2), 256, 0, stream>>>(nvpT, nhpT, NH, NB, NB / 2, diff0);

  // 5) parameter updates + error
  wupdate_kernel<<<dim3((NV * NH / 4) / 256), 256, 0, stream>>>(W, wmom, diff0, diff1,
                                                                (float*)d_out + 1);
  biaserr_kernel<<<dim3(16), 256, 0, stream>>>(vb, vbmom, vbcs, hb, hbmom, phpcs, nhpcs, errp,
                                               (float*)d_out);
}